// Round 1
// baseline (7806.311 us; speedup 1.0000x reference)
//
#include <hip/hip_runtime.h>

#define Bq 128
#define Tq 256
#define Dq 512
#define Hq 1024
#define N4H 4096
#define KTOT 1536  // Dq + Hq

typedef __attribute__((ext_vector_type(8))) short bf16x8;
typedef __attribute__((ext_vector_type(4))) float f32x4;

static __device__ __forceinline__ unsigned short f2bf(float x) {
    unsigned int u = __builtin_bit_cast(unsigned int, x);
    u = (u + 0x7FFFu + ((u >> 16) & 1u)) >> 16;
    return (unsigned short)u;
}
static __device__ __forceinline__ float bf2f(unsigned short h) {
    unsigned int u = ((unsigned int)h) << 16;
    return __builtin_bit_cast(float, u);
}

// ---- pack weights: Wp[n][k] bf16, n in [0,4096), k in [0,1536): k<512 from Kw, else Rw
__global__ __launch_bounds__(256) void pack_w(const float* __restrict__ Kw,
                                              const float* __restrict__ Rw,
                                              unsigned short* __restrict__ Wp) {
    __shared__ float tile[32][33];
    int nt = blockIdx.x * 32;
    int kt = blockIdx.y * 32;
    int tx = threadIdx.x, ty = threadIdx.y;  // 32 x 8
#pragma unroll
    for (int i = 0; i < 32; i += 8) {
        int k = kt + ty + i;
        int n = nt + tx;
        float v = (k < Dq) ? Kw[(size_t)k * N4H + n] : Rw[(size_t)(k - Dq) * N4H + n];
        tile[ty + i][tx] = v;
    }
    __syncthreads();
#pragma unroll
    for (int i = 0; i < 32; i += 8) {
        int n = nt + ty + i;
        int k = kt + tx;
        Wp[(size_t)n * KTOT + k] = f2bf(tile[tx][ty + i]);
    }
}

// ---- cast input to bf16 (same [B][T][D] layout)
__global__ __launch_bounds__(256) void pack_x(const float* __restrict__ X,
                                              unsigned short* __restrict__ Xb) {
    size_t base = ((size_t)blockIdx.x * 256 + threadIdx.x) * 8;
    float4 v0 = *(const float4*)(X + base);
    float4 v1 = *(const float4*)(X + base + 4);
    bf16x8 r;
    r[0] = (short)f2bf(v0.x); r[1] = (short)f2bf(v0.y);
    r[2] = (short)f2bf(v0.z); r[3] = (short)f2bf(v0.w);
    r[4] = (short)f2bf(v1.x); r[5] = (short)f2bf(v1.y);
    r[6] = (short)f2bf(v1.z); r[7] = (short)f2bf(v1.w);
    *(bf16x8*)(Xb + base) = r;
}

// ---- zero h[0] and c
__global__ __launch_bounds__(256) void init_hc(unsigned short* __restrict__ Hb,
                                               float* __restrict__ Cs) {
    int i = blockIdx.x * 256 + threadIdx.x;  // 131072 total
    Hb[i] = 0;
    Cs[i] = 0.f;
}

// ---- one LSTM timestep, fused GEMM + gates.
// grid 128 wgs; wg owns hidden units [wg*8, wg*8+8) -> 32 cols (4 gates), all 128 rows.
// 4 waves: wave w handles rows [32w, 32w+32).
__global__ __launch_bounds__(256) void lstm_step(
    const unsigned short* __restrict__ Wp,
    const unsigned short* __restrict__ Xb,
    const float* __restrict__ bias,
    const unsigned short* __restrict__ Hcur,
    unsigned short* __restrict__ Hnxt,
    float* __restrict__ Cs,
    int t) {
    const int wg = blockIdx.x;
    const int hs0 = wg * 8;
    const int tid = threadIdx.x;
    const int wave = tid >> 6;
    const int lane = tid & 63;
    const int rowb = wave * 32;
    const int c16 = lane & 15;
    const int kg = lane >> 4;

    // tile0 cols: q=0(i) for c16<8, q=1(f) for c16>=8 ; tile1: q=2(g)/q=3(o)
    const int col0 = ((c16 >> 3)) * Hq + hs0 + (c16 & 7);
    const int col1 = ((c16 >> 3) + 2) * Hq + hs0 + (c16 & 7);

    const int arow0 = rowb + c16;
    const int arow1 = arow0 + 16;

    const unsigned short* xr0 = Xb + ((size_t)arow0 * Tq + t) * Dq + kg * 8;
    const unsigned short* xr1 = Xb + ((size_t)arow1 * Tq + t) * Dq + kg * 8;
    const unsigned short* hr0 = Hcur + (size_t)arow0 * Hq + kg * 8;
    const unsigned short* hr1 = Hcur + (size_t)arow1 * Hq + kg * 8;
    const unsigned short* wb0 = Wp + (size_t)col0 * KTOT + kg * 8;
    const unsigned short* wb1 = Wp + (size_t)col1 * KTOT + kg * 8;

    f32x4 acc00 = {0.f, 0.f, 0.f, 0.f};
    f32x4 acc01 = {0.f, 0.f, 0.f, 0.f};
    f32x4 acc10 = {0.f, 0.f, 0.f, 0.f};
    f32x4 acc11 = {0.f, 0.f, 0.f, 0.f};

#pragma unroll 4
    for (int kc = 0; kc < 16; ++kc) {
        int k0 = kc * 32;
        bf16x8 a0 = *(const bf16x8*)(xr0 + k0);
        bf16x8 a1 = *(const bf16x8*)(xr1 + k0);
        bf16x8 b0 = *(const bf16x8*)(wb0 + k0);
        bf16x8 b1 = *(const bf16x8*)(wb1 + k0);
        acc00 = __builtin_amdgcn_mfma_f32_16x16x32_bf16(a0, b0, acc00, 0, 0, 0);
        acc01 = __builtin_amdgcn_mfma_f32_16x16x32_bf16(a0, b1, acc01, 0, 0, 0);
        acc10 = __builtin_amdgcn_mfma_f32_16x16x32_bf16(a1, b0, acc10, 0, 0, 0);
        acc11 = __builtin_amdgcn_mfma_f32_16x16x32_bf16(a1, b1, acc11, 0, 0, 0);
    }
#pragma unroll 4
    for (int kc = 0; kc < 32; ++kc) {
        int kh = kc * 32;
        int kw = Dq + kh;
        bf16x8 a0 = *(const bf16x8*)(hr0 + kh);
        bf16x8 a1 = *(const bf16x8*)(hr1 + kh);
        bf16x8 b0 = *(const bf16x8*)(wb0 + kw);
        bf16x8 b1 = *(const bf16x8*)(wb1 + kw);
        acc00 = __builtin_amdgcn_mfma_f32_16x16x32_bf16(a0, b0, acc00, 0, 0, 0);
        acc01 = __builtin_amdgcn_mfma_f32_16x16x32_bf16(a0, b1, acc01, 0, 0, 0);
        acc10 = __builtin_amdgcn_mfma_f32_16x16x32_bf16(a1, b0, acc10, 0, 0, 0);
        acc11 = __builtin_amdgcn_mfma_f32_16x16x32_bf16(a1, b1, acc11, 0, 0, 0);
    }

    const float bias0 = bias[col0];
    const float bias1 = bias[col1];
    const bool hi = (c16 & 8) != 0;
    const int j = hs0 + (c16 & 7);

#pragma unroll
    for (int m = 0; m < 2; ++m) {
        f32x4 z0 = m ? acc10 : acc00;
        f32x4 z1 = m ? acc11 : acc01;
#pragma unroll
        for (int r = 0; r < 4; ++r) {
            float za = z0[r] + bias0;
            float zb = z1[r] + bias1;
            float pa = __shfl_xor(za, 8, 64);
            float pb = __shfl_xor(zb, 8, 64);
            float zi = hi ? pa : za;
            float zf = hi ? za : pa;
            float zg = hi ? pb : zb;
            float zo = hi ? zb : pb;
            float gi = 1.f / (1.f + expf(-zi));
            float gf = 1.f / (1.f + expf(-zf));
            float gg = tanhf(zg);
            float go = 1.f / (1.f + expf(-zo));
            int b = rowb + m * 16 + kg * 4 + r;
            size_t cidx = (size_t)b * Hq + j;
            float cp = Cs[cidx];
            float cn = gf * cp + gi * gg;
            float hn = go * tanhf(cn);
            if (!hi) {
                Cs[cidx] = cn;
                Hnxt[cidx] = f2bf(hn);
            }
        }
    }
}

// ---- final dense + sigmoid: out[b] = sigmoid(h_last[b,:] @ w + b0)
__global__ __launch_bounds__(256) void dense_k(const unsigned short* __restrict__ H0,
                                               const float* __restrict__ w,
                                               const float* __restrict__ b0,
                                               float* __restrict__ out) {
    __shared__ float red[4];
    int b = blockIdx.x, tid = threadIdx.x;
    float s = 0.f;
    for (int j = tid; j < Hq; j += 256) s += bf2f(H0[(size_t)b * Hq + j]) * w[j];
#pragma unroll
    for (int off = 32; off > 0; off >>= 1) s += __shfl_down(s, off, 64);
    if ((tid & 63) == 0) red[tid >> 6] = s;
    __syncthreads();
    if (tid == 0) {
        float tot = red[0] + red[1] + red[2] + red[3] + b0[0];
        out[b] = 1.f / (1.f + expf(-tot));
    }
}

extern "C" void kernel_launch(void* const* d_in, const int* in_sizes, int n_in,
                              void* d_out, int out_size, void* d_ws, size_t ws_size,
                              hipStream_t stream) {
    const float* X = (const float*)d_in[0];
    const float* Kw = (const float*)d_in[1];
    const float* Rw = (const float*)d_in[2];
    const float* bias = (const float*)d_in[3];
    const float* dw = (const float*)d_in[4];
    const float* db = (const float*)d_in[5];
    float* out = (float*)d_out;
    char* ws = (char*)d_ws;

    // workspace layout (bytes):
    //   Wp  bf16 [4096][1536]        @ 0         (12,582,912)
    //   Xb  bf16 [128][256][512]     @ 12582912  (33,554,432)
    //   Hb  bf16 [2][128][1024]      @ 46137344  (524,288)
    //   Cs  f32  [128][1024]         @ 46661632  (524,288)   -> total ~47.2 MB
    unsigned short* Wp = (unsigned short*)(ws);
    unsigned short* Xb = (unsigned short*)(ws + 12582912);
    unsigned short* Hb = (unsigned short*)(ws + 46137344);
    float* Cs = (float*)(ws + 46661632);

    pack_w<<<dim3(128, 48), dim3(32, 8), 0, stream>>>(Kw, Rw, Wp);
    pack_x<<<8192, 256, 0, stream>>>(X, Xb);
    init_hc<<<512, 256, 0, stream>>>(Hb, Cs);

    for (int t = 0; t < Tq; ++t) {
        const unsigned short* Hcur = Hb + (size_t)(t & 1) * (Bq * Hq);
        unsigned short* Hnxt = Hb + (size_t)((t + 1) & 1) * (Bq * Hq);
        lstm_step<<<128, 256, 0, stream>>>(Wp, Xb, bias, Hcur, Hnxt, Cs, t);
    }
    // after t=255 the freshest h is in buffer 0
    dense_k<<<128, 256, 0, stream>>>(Hb, dw, db, out);
}

// Round 2
// 7634.682 us; speedup vs baseline: 1.0225x; 1.0225x over previous
//
#include <hip/hip_runtime.h>

#define Bq 128
#define Tq 256
#define Dq 512
#define Hq 1024
#define N4H 4096
#define KTOT 1536
#define LDW 1544   // LDS row stride in ushorts (1536 + 8 pad -> stride%32words==4, conflict-free b128)
#define NWG 128

typedef __attribute__((ext_vector_type(8))) short bf16x8;
typedef __attribute__((ext_vector_type(4))) float f32x4;

static __device__ __forceinline__ unsigned short f2bf(float x) {
    unsigned int u = __builtin_bit_cast(unsigned int, x);
    u = (u + 0x7FFFu + ((u >> 16) & 1u)) >> 16;
    return (unsigned short)u;
}
static __device__ __forceinline__ float bf2f(unsigned short h) {
    unsigned int u = ((unsigned int)h) << 16;
    return __builtin_bit_cast(float, u);
}
static __device__ __forceinline__ float sigm(float x) {
    return 1.f / (1.f + __expf(-x));
}
static __device__ __forceinline__ float tanh_f(float x) {
    return 2.f / (1.f + __expf(-2.f * x)) - 1.f;
}

// ---- pack weights: Wp[n][k] bf16, n in [0,4096), k<512 from Kw, else Rw
__global__ __launch_bounds__(256) void pack_w(const float* __restrict__ Kw,
                                              const float* __restrict__ Rw,
                                              unsigned short* __restrict__ Wp) {
    __shared__ float tile[32][33];
    int nt = blockIdx.x * 32;
    int kt = blockIdx.y * 32;
    int tx = threadIdx.x, ty = threadIdx.y;  // 32 x 8
#pragma unroll
    for (int i = 0; i < 32; i += 8) {
        int k = kt + ty + i;
        int n = nt + tx;
        float v = (k < Dq) ? Kw[(size_t)k * N4H + n] : Rw[(size_t)(k - Dq) * N4H + n];
        tile[ty + i][tx] = v;
    }
    __syncthreads();
#pragma unroll
    for (int i = 0; i < 32; i += 8) {
        int n = nt + ty + i;
        int k = kt + tx;
        Wp[(size_t)n * KTOT + k] = f2bf(tile[tx][ty + i]);
    }
}

// ---- cast + transpose input to bf16 [T][B][D]
__global__ __launch_bounds__(256) void pack_x(const float* __restrict__ X,
                                              unsigned short* __restrict__ Xb) {
    int gid = blockIdx.x * 256 + threadIdx.x;  // 2,097,152 chunks of 8
    int dc = gid & 63;
    int t = (gid >> 6) & 255;
    int b = gid >> 14;
    const float* src = X + ((size_t)b * Tq + t) * Dq + dc * 8;
    float4 v0 = *(const float4*)src;
    float4 v1 = *(const float4*)(src + 4);
    bf16x8 r;
    r[0] = (short)f2bf(v0.x); r[1] = (short)f2bf(v0.y);
    r[2] = (short)f2bf(v0.z); r[3] = (short)f2bf(v0.w);
    r[4] = (short)f2bf(v1.x); r[5] = (short)f2bf(v1.y);
    r[6] = (short)f2bf(v1.z); r[7] = (short)f2bf(v1.w);
    *(bf16x8*)(Xb + ((size_t)t * Bq + b) * Dq + dc * 8) = r;
}

// ---- zero h buffer 0 + barrier state
__global__ __launch_bounds__(256) void init_ws(unsigned short* __restrict__ Hb,
                                               unsigned* __restrict__ bar) {
    int i = blockIdx.x * 256 + threadIdx.x;  // 131072
    Hb[i] = 0;
    if (i < 2) bar[i] = 0;
}

__device__ __forceinline__ void grid_barrier(unsigned* cnt, unsigned* gen) {
    __syncthreads();  // each wave drains its own vmem before s_barrier
    if (threadIdx.x == 0) {
        __threadfence();  // agent-scope release: L2 writeback so other XCDs see h
        unsigned g = __hip_atomic_load(gen, __ATOMIC_RELAXED, __HIP_MEMORY_SCOPE_AGENT);
        unsigned a = __hip_atomic_fetch_add(cnt, 1u, __ATOMIC_ACQ_REL, __HIP_MEMORY_SCOPE_AGENT);
        if (a == NWG - 1) {
            __hip_atomic_store(cnt, 0u, __ATOMIC_RELAXED, __HIP_MEMORY_SCOPE_AGENT);
            __hip_atomic_store(gen, g + 1u, __ATOMIC_RELEASE, __HIP_MEMORY_SCOPE_AGENT);
        } else {
            while (__hip_atomic_load(gen, __ATOMIC_ACQUIRE, __HIP_MEMORY_SCOPE_AGENT) == g) {
                __builtin_amdgcn_s_sleep(1);
            }
        }
        __threadfence();  // acquire: invalidate stale L1/L2 before reading new h
    }
    __syncthreads();
}

// ---- persistent LSTM: 128 wgs, wg owns 8 hidden units (32 gate-cols), all 128 rows.
// 4 waves: wave w handles rows [32w, 32w+32). Weights live in LDS, c in registers.
__global__ __launch_bounds__(256) void lstm_persist(
    const unsigned short* __restrict__ Wp,
    const unsigned short* __restrict__ Xb,
    const float* __restrict__ bias,
    unsigned short* __restrict__ Hb,
    const float* __restrict__ dw,
    const float* __restrict__ db,
    float* __restrict__ out,
    unsigned* __restrict__ bar) {
    extern __shared__ unsigned short Wl[];  // 32 * LDW ushorts = 98,816 B
    __shared__ float red[4];

    const int wg = blockIdx.x;
    const int hs0 = wg * 8;
    const int tid = threadIdx.x;
    const int wave = tid >> 6;
    const int lane = tid & 63;
    const int rowb = wave * 32;
    const int c16 = lane & 15;
    const int kg = lane >> 4;

    // load this wg's 32 weight columns into LDS (once)
    for (int c = tid; c < 32 * 192; c += 256) {
        int lc = c / 192;   // local col: q*8+u
        int pos = c % 192;  // bf16x8 chunk within row
        int q = lc >> 3, u = lc & 7;
        bf16x8 v = *(const bf16x8*)(Wp + (size_t)(q * Hq + hs0 + u) * KTOT + pos * 8);
        *(bf16x8*)(&Wl[lc * LDW + pos * 8]) = v;
    }

    const int col0 = (c16 >> 3) * Hq + hs0 + (c16 & 7);
    const int col1 = ((c16 >> 3) + 2) * Hq + hs0 + (c16 & 7);
    const float bias0 = bias[col0];
    const float bias1 = bias[col1];
    const bool hi = (c16 & 8) != 0;
    const int j = hs0 + (c16 & 7);
    const int arow0 = rowb + c16;
    const int arow1 = arow0 + 16;
    const int wl0 = c16 * LDW + kg * 8;
    const int wl1 = (16 + c16) * LDW + kg * 8;

    float creg[8];
#pragma unroll
    for (int i = 0; i < 8; ++i) creg[i] = 0.f;

    __syncthreads();

    for (int t = 0; t < Tq; ++t) {
        const unsigned short* Hcur = Hb + (size_t)(t & 1) * (Bq * Hq);
        unsigned short* Hnxt = Hb + (size_t)((t + 1) & 1) * (Bq * Hq);

        const unsigned short* xr0 = Xb + ((size_t)t * Bq + arow0) * Dq + kg * 8;
        const unsigned short* xr1 = Xb + ((size_t)t * Bq + arow1) * Dq + kg * 8;
        const unsigned short* hr0 = Hcur + (size_t)arow0 * Hq + kg * 8;
        const unsigned short* hr1 = Hcur + (size_t)arow1 * Hq + kg * 8;

        f32x4 acc00 = {0.f, 0.f, 0.f, 0.f};
        f32x4 acc01 = {0.f, 0.f, 0.f, 0.f};
        f32x4 acc10 = {0.f, 0.f, 0.f, 0.f};
        f32x4 acc11 = {0.f, 0.f, 0.f, 0.f};

#pragma unroll 4
        for (int kc = 0; kc < 16; ++kc) {
            bf16x8 a0 = *(const bf16x8*)(xr0 + kc * 32);
            bf16x8 a1 = *(const bf16x8*)(xr1 + kc * 32);
            bf16x8 b0 = *(const bf16x8*)(&Wl[wl0 + kc * 32]);
            bf16x8 b1 = *(const bf16x8*)(&Wl[wl1 + kc * 32]);
            acc00 = __builtin_amdgcn_mfma_f32_16x16x32_bf16(a0, b0, acc00, 0, 0, 0);
            acc01 = __builtin_amdgcn_mfma_f32_16x16x32_bf16(a0, b1, acc01, 0, 0, 0);
            acc10 = __builtin_amdgcn_mfma_f32_16x16x32_bf16(a1, b0, acc10, 0, 0, 0);
            acc11 = __builtin_amdgcn_mfma_f32_16x16x32_bf16(a1, b1, acc11, 0, 0, 0);
        }
#pragma unroll 4
        for (int kc = 0; kc < 32; ++kc) {
            bf16x8 a0 = *(const bf16x8*)(hr0 + kc * 32);
            bf16x8 a1 = *(const bf16x8*)(hr1 + kc * 32);
            bf16x8 b0 = *(const bf16x8*)(&Wl[wl0 + 512 + kc * 32]);
            bf16x8 b1 = *(const bf16x8*)(&Wl[wl1 + 512 + kc * 32]);
            acc00 = __builtin_amdgcn_mfma_f32_16x16x32_bf16(a0, b0, acc00, 0, 0, 0);
            acc01 = __builtin_amdgcn_mfma_f32_16x16x32_bf16(a0, b1, acc01, 0, 0, 0);
            acc10 = __builtin_amdgcn_mfma_f32_16x16x32_bf16(a1, b0, acc10, 0, 0, 0);
            acc11 = __builtin_amdgcn_mfma_f32_16x16x32_bf16(a1, b1, acc11, 0, 0, 0);
        }

#pragma unroll
        for (int m = 0; m < 2; ++m) {
            f32x4 z0 = m ? acc10 : acc00;
            f32x4 z1 = m ? acc11 : acc01;
#pragma unroll
            for (int r = 0; r < 4; ++r) {
                float za = z0[r] + bias0;
                float zb = z1[r] + bias1;
                float pa = __shfl_xor(za, 8, 64);
                float pb = __shfl_xor(zb, 8, 64);
                float zi = hi ? pa : za;
                float zf = hi ? za : pa;
                float zg = hi ? pb : zb;
                float zo = hi ? zb : pb;
                float gi = sigm(zi);
                float gf = sigm(zf);
                float go = sigm(zo);
                float gg = tanh_f(zg);
                float cn = gf * creg[m * 4 + r] + gi * gg;
                creg[m * 4 + r] = cn;
                float hn = go * tanh_f(cn);
                if (!hi) {
                    int b = rowb + m * 16 + kg * 4 + r;
                    Hnxt[(size_t)b * Hq + j] = f2bf(hn);
                }
            }
        }

        grid_barrier(&bar[0], &bar[1]);
    }

    // dense head: wg handles batch row b = wg; final h is in buffer 0
    {
        const unsigned short* hl = Hb + (size_t)wg * Hq;
        float s = 0.f;
        for (int jj = tid; jj < Hq; jj += 256) s += bf2f(hl[jj]) * dw[jj];
#pragma unroll
        for (int off = 32; off > 0; off >>= 1) s += __shfl_down(s, off, 64);
        if (lane == 0) red[wave] = s;
        __syncthreads();
        if (tid == 0) out[wg] = 1.f / (1.f + __expf(-(red[0] + red[1] + red[2] + red[3] + db[0])));
    }
}

extern "C" void kernel_launch(void* const* d_in, const int* in_sizes, int n_in,
                              void* d_out, int out_size, void* d_ws, size_t ws_size,
                              hipStream_t stream) {
    const float* X = (const float*)d_in[0];
    const float* Kw = (const float*)d_in[1];
    const float* Rw = (const float*)d_in[2];
    const float* bias = (const float*)d_in[3];
    const float* dw = (const float*)d_in[4];
    const float* db = (const float*)d_in[5];
    float* out = (float*)d_out;
    char* ws = (char*)d_ws;

    // workspace layout:
    //   Wp  bf16 [4096][1536]     @ 0          (12,582,912)
    //   Xb  bf16 [256][128][512]  @ 12,582,912 (33,554,432)   [T][B][D]
    //   Hb  bf16 [2][128][1024]   @ 46,137,344 (524,288)
    //   bar u32  [2]              @ 46,661,632 (8)
    unsigned short* Wp = (unsigned short*)(ws);
    unsigned short* Xb = (unsigned short*)(ws + 12582912);
    unsigned short* Hb = (unsigned short*)(ws + 46137344);
    unsigned* bar = (unsigned*)(ws + 46661632);

    pack_w<<<dim3(128, 48), dim3(32, 8), 0, stream>>>(Kw, Rw, Wp);
    pack_x<<<8192, 256, 0, stream>>>(X, Xb);
    init_ws<<<512, 256, 0, stream>>>(Hb, bar);

    size_t lds_bytes = (size_t)32 * LDW * sizeof(unsigned short);  // 98,816
    lstm_persist<<<NWG, 256, lds_bytes, stream>>>(Wp, Xb, bias, Hb, dw, db, out, bar);
}

// Round 4
// 4717.038 us; speedup vs baseline: 1.6549x; 1.6185x over previous
//
#include <hip/hip_runtime.h>

#define Bq 128
#define Tq 256
#define Dq 512
#define Hq 1024
#define N4H 4096
#define KTOT 1536
#define LDW 1544   // LDS row stride in ushorts (stride%32words==4 -> 2-way (free) on b128)
#define NWG 128

typedef __attribute__((ext_vector_type(8))) short bf16x8;
typedef __attribute__((ext_vector_type(4))) float f32x4;

static __device__ __forceinline__ unsigned short f2bf(float x) {
    unsigned int u = __builtin_bit_cast(unsigned int, x);
    u = (u + 0x7FFFu + ((u >> 16) & 1u)) >> 16;
    return (unsigned short)u;
}
static __device__ __forceinline__ float bf2f(unsigned short h) {
    unsigned int u = ((unsigned int)h) << 16;
    return __builtin_bit_cast(float, u);
}
static __device__ __forceinline__ float sigm(float x) {
    return 1.f / (1.f + __expf(-x));
}
static __device__ __forceinline__ float tanh_f(float x) {
    return 2.f / (1.f + __expf(-2.f * x)) - 1.f;
}

// ---- pack weights: Wp[n][k] bf16, n in [0,4096), k<512 from Kw, else Rw
__global__ __launch_bounds__(256) void pack_w(const float* __restrict__ Kw,
                                              const float* __restrict__ Rw,
                                              unsigned short* __restrict__ Wp) {
    __shared__ float tile[32][33];
    int nt = blockIdx.x * 32;
    int kt = blockIdx.y * 32;
    int tx = threadIdx.x, ty = threadIdx.y;  // 32 x 8
#pragma unroll
    for (int i = 0; i < 32; i += 8) {
        int k = kt + ty + i;
        int n = nt + tx;
        float v = (k < Dq) ? Kw[(size_t)k * N4H + n] : Rw[(size_t)(k - Dq) * N4H + n];
        tile[ty + i][tx] = v;
    }
    __syncthreads();
#pragma unroll
    for (int i = 0; i < 32; i += 8) {
        int n = nt + ty + i;
        int k = kt + tx;
        Wp[(size_t)n * KTOT + k] = f2bf(tile[tx][ty + i]);
    }
}

// ---- cast + transpose input to bf16 [T][B][D]
__global__ __launch_bounds__(256) void pack_x(const float* __restrict__ X,
                                              unsigned short* __restrict__ Xb) {
    int gid = blockIdx.x * 256 + threadIdx.x;  // 2,097,152 chunks of 8
    int dc = gid & 63;
    int t = (gid >> 6) & 255;
    int b = gid >> 14;
    const float* src = X + ((size_t)b * Tq + t) * Dq + dc * 8;
    float4 v0 = *(const float4*)src;
    float4 v1 = *(const float4*)(src + 4);
    bf16x8 r;
    r[0] = (short)f2bf(v0.x); r[1] = (short)f2bf(v0.y);
    r[2] = (short)f2bf(v0.z); r[3] = (short)f2bf(v0.w);
    r[4] = (short)f2bf(v1.x); r[5] = (short)f2bf(v1.y);
    r[6] = (short)f2bf(v1.z); r[7] = (short)f2bf(v1.w);
    *(bf16x8*)(Xb + ((size_t)t * Bq + b) * Dq + dc * 8) = r;
}

// ---- zero h buffer 0 + barrier counter
__global__ __launch_bounds__(256) void init_ws(unsigned short* __restrict__ Hb,
                                               unsigned* __restrict__ bar) {
    int i = blockIdx.x * 256 + threadIdx.x;  // 131072
    Hb[i] = 0;
    if (i < 2) bar[i] = 0;
}

// ---- persistent LSTM: 128 wgs, wg owns 8 hidden units (32 gate-cols), all 128 rows.
// 4 waves: wave w handles rows [32w, 32w+32). Weights in LDS, c in registers.
// Grid barrier: monotone counter, relaxed polls, ONE acquire fence per step.
__global__ __launch_bounds__(256) void lstm_persist(
    const unsigned short* __restrict__ Wp,
    const unsigned short* __restrict__ Xb,
    const float* __restrict__ bias,
    unsigned short* __restrict__ Hb,
    const float* __restrict__ dw,
    const float* __restrict__ db,
    float* __restrict__ out,
    unsigned* __restrict__ bar) {
    extern __shared__ unsigned short Wl[];  // 32 * LDW ushorts = 98,816 B
    __shared__ float red[4];

    const int wg = blockIdx.x;
    const int hs0 = wg * 8;
    const int tid = threadIdx.x;
    const int wave = tid >> 6;
    const int lane = tid & 63;
    const int rowb = wave * 32;
    const int c16 = lane & 15;
    const int kg = lane >> 4;

    // load this wg's 32 weight columns into LDS (once)
    for (int c = tid; c < 32 * 192; c += 256) {
        int lc = c / 192;   // local col: q*8+u
        int pos = c % 192;  // bf16x8 chunk within row
        int q = lc >> 3, u = lc & 7;
        bf16x8 v = *(const bf16x8*)(Wp + (size_t)(q * Hq + hs0 + u) * KTOT + pos * 8);
        *(bf16x8*)(&Wl[lc * LDW + pos * 8]) = v;
    }

    const int col0 = (c16 >> 3) * Hq + hs0 + (c16 & 7);
    const int col1 = ((c16 >> 3) + 2) * Hq + hs0 + (c16 & 7);
    const float bias0 = bias[col0];
    const float bias1 = bias[col1];
    const bool hi = (c16 & 8) != 0;
    const int j = hs0 + (c16 & 7);
    const int arow0 = rowb + c16;
    const int arow1 = arow0 + 16;
    const int wl0 = c16 * LDW + kg * 8;
    const int wl1 = (16 + c16) * LDW + kg * 8;

    float creg[8];
#pragma unroll
    for (int i = 0; i < 8; ++i) creg[i] = 0.f;

    __syncthreads();

    // x-part accumulators for the upcoming step (computed one step ahead)
    f32x4 xa00 = {0.f, 0.f, 0.f, 0.f};
    f32x4 xa01 = {0.f, 0.f, 0.f, 0.f};
    f32x4 xa10 = {0.f, 0.f, 0.f, 0.f};
    f32x4 xa11 = {0.f, 0.f, 0.f, 0.f};
    {
        const unsigned short* xr0 = Xb + ((size_t)arow0) * Dq + kg * 8;
        const unsigned short* xr1 = Xb + ((size_t)arow1) * Dq + kg * 8;
#pragma unroll 4
        for (int kc = 0; kc < 16; ++kc) {
            bf16x8 a0 = *(const bf16x8*)(xr0 + kc * 32);
            bf16x8 a1 = *(const bf16x8*)(xr1 + kc * 32);
            bf16x8 b0 = *(const bf16x8*)(&Wl[wl0 + kc * 32]);
            bf16x8 b1 = *(const bf16x8*)(&Wl[wl1 + kc * 32]);
            xa00 = __builtin_amdgcn_mfma_f32_16x16x32_bf16(a0, b0, xa00, 0, 0, 0);
            xa01 = __builtin_amdgcn_mfma_f32_16x16x32_bf16(a0, b1, xa01, 0, 0, 0);
            xa10 = __builtin_amdgcn_mfma_f32_16x16x32_bf16(a1, b0, xa10, 0, 0, 0);
            xa11 = __builtin_amdgcn_mfma_f32_16x16x32_bf16(a1, b1, xa11, 0, 0, 0);
        }
    }

    for (int t = 0; t < Tq; ++t) {
        const unsigned short* Hcur = Hb + (size_t)(t & 1) * (Bq * Hq);
        unsigned short* Hnxt = Hb + (size_t)((t + 1) & 1) * (Bq * Hq);

        const unsigned short* hr0 = Hcur + (size_t)arow0 * Hq + kg * 8;
        const unsigned short* hr1 = Hcur + (size_t)arow1 * Hq + kg * 8;

        f32x4 acc00 = xa00, acc01 = xa01, acc10 = xa10, acc11 = xa11;

#pragma unroll 4
        for (int kc = 0; kc < 32; ++kc) {
            bf16x8 a0 = *(const bf16x8*)(hr0 + kc * 32);
            bf16x8 a1 = *(const bf16x8*)(hr1 + kc * 32);
            bf16x8 b0 = *(const bf16x8*)(&Wl[wl0 + 512 + kc * 32]);
            bf16x8 b1 = *(const bf16x8*)(&Wl[wl1 + 512 + kc * 32]);
            acc00 = __builtin_amdgcn_mfma_f32_16x16x32_bf16(a0, b0, acc00, 0, 0, 0);
            acc01 = __builtin_amdgcn_mfma_f32_16x16x32_bf16(a0, b1, acc01, 0, 0, 0);
            acc10 = __builtin_amdgcn_mfma_f32_16x16x32_bf16(a1, b0, acc10, 0, 0, 0);
            acc11 = __builtin_amdgcn_mfma_f32_16x16x32_bf16(a1, b1, acc11, 0, 0, 0);
        }

#pragma unroll
        for (int m = 0; m < 2; ++m) {
            f32x4 z0 = m ? acc10 : acc00;
            f32x4 z1 = m ? acc11 : acc01;
#pragma unroll
            for (int r = 0; r < 4; ++r) {
                float za = z0[r] + bias0;
                float zb = z1[r] + bias1;
                float pa = __shfl_xor(za, 8, 64);
                float pb = __shfl_xor(zb, 8, 64);
                float zi = hi ? pa : za;
                float zf = hi ? za : pa;
                float zg = hi ? pb : zb;
                float zo = hi ? zb : pb;
                float gi = sigm(zi);
                float gf = sigm(zf);
                float go = sigm(zo);
                float gg = tanh_f(zg);
                float cn = gf * creg[m * 4 + r] + gi * gg;
                creg[m * 4 + r] = cn;
                float hn = go * tanh_f(cn);
                if (!hi) {
                    int b = rowb + m * 16 + kg * 4 + r;
                    Hnxt[(size_t)b * Hq + j] = f2bf(hn);
                }
            }
        }

        // ---- arrive (h stores drained by __syncthreads' vmcnt(0); release pushes them to IF$)
        __syncthreads();
        if (tid == 0) {
            __builtin_amdgcn_fence(__ATOMIC_RELEASE, "agent");
            __hip_atomic_fetch_add(bar, 1u, __ATOMIC_RELAXED, __HIP_MEMORY_SCOPE_AGENT);
        }

        // ---- overlap: x-part GEMM for step t+1 (h-independent) while others arrive
        xa00 = (f32x4){0.f, 0.f, 0.f, 0.f};
        xa01 = (f32x4){0.f, 0.f, 0.f, 0.f};
        xa10 = (f32x4){0.f, 0.f, 0.f, 0.f};
        xa11 = (f32x4){0.f, 0.f, 0.f, 0.f};
        if (t + 1 < Tq) {
            const unsigned short* xr0 = Xb + ((size_t)(t + 1) * Bq + arow0) * Dq + kg * 8;
            const unsigned short* xr1 = Xb + ((size_t)(t + 1) * Bq + arow1) * Dq + kg * 8;
#pragma unroll 4
            for (int kc = 0; kc < 16; ++kc) {
                bf16x8 a0 = *(const bf16x8*)(xr0 + kc * 32);
                bf16x8 a1 = *(const bf16x8*)(xr1 + kc * 32);
                bf16x8 b0 = *(const bf16x8*)(&Wl[wl0 + kc * 32]);
                bf16x8 b1 = *(const bf16x8*)(&Wl[wl1 + kc * 32]);
                xa00 = __builtin_amdgcn_mfma_f32_16x16x32_bf16(a0, b0, xa00, 0, 0, 0);
                xa01 = __builtin_amdgcn_mfma_f32_16x16x32_bf16(a0, b1, xa01, 0, 0, 0);
                xa10 = __builtin_amdgcn_mfma_f32_16x16x32_bf16(a1, b0, xa10, 0, 0, 0);
                xa11 = __builtin_amdgcn_mfma_f32_16x16x32_bf16(a1, b1, xa11, 0, 0, 0);
            }
        }

        // ---- wait: RELAXED polls (no cache maintenance), then ONE acquire fence
        if (tid == 0) {
            const unsigned target = (unsigned)(t + 1) * NWG;
            while (__hip_atomic_load(bar, __ATOMIC_RELAXED, __HIP_MEMORY_SCOPE_AGENT) < target) {
                __builtin_amdgcn_s_sleep(2);
            }
            __builtin_amdgcn_fence(__ATOMIC_ACQUIRE, "agent");
        }
        __syncthreads();
    }

    // dense head: wg handles batch row b = wg; final h is in buffer 0 (t=256 even)
    {
        const unsigned short* hl = Hb + (size_t)wg * Hq;
        float s = 0.f;
        for (int jj = tid; jj < Hq; jj += 256) s += bf2f(hl[jj]) * dw[jj];
#pragma unroll
        for (int off = 32; off > 0; off >>= 1) s += __shfl_down(s, off, 64);
        if (lane == 0) red[wave] = s;
        __syncthreads();
        if (tid == 0) out[wg] = 1.f / (1.f + __expf(-(red[0] + red[1] + red[2] + red[3] + db[0])));
    }
}

extern "C" void kernel_launch(void* const* d_in, const int* in_sizes, int n_in,
                              void* d_out, int out_size, void* d_ws, size_t ws_size,
                              hipStream_t stream) {
    const float* X = (const float*)d_in[0];
    const float* Kw = (const float*)d_in[1];
    const float* Rw = (const float*)d_in[2];
    const float* bias = (const float*)d_in[3];
    const float* dw = (const float*)d_in[4];
    const float* db = (const float*)d_in[5];
    float* out = (float*)d_out;
    char* ws = (char*)d_ws;

    // workspace layout:
    //   Wp  bf16 [4096][1536]     @ 0          (12,582,912)
    //   Xb  bf16 [256][128][512]  @ 12,582,912 (33,554,432)   [T][B][D]
    //   Hb  bf16 [2][128][1024]   @ 46,137,344 (524,288)
    //   bar u32  [2]              @ 46,661,632 (8)
    unsigned short* Wp = (unsigned short*)(ws);
    unsigned short* Xb = (unsigned short*)(ws + 12582912);
    unsigned short* Hb = (unsigned short*)(ws + 46137344);
    unsigned* bar = (unsigned*)(ws + 46661632);

    pack_w<<<dim3(128, 48), dim3(32, 8), 0, stream>>>(Kw, Rw, Wp);
    pack_x<<<8192, 256, 0, stream>>>(X, Xb);
    init_ws<<<512, 256, 0, stream>>>(Hb, bar);

    size_t lds_bytes = (size_t)32 * LDW * sizeof(unsigned short);  // 98,816
    lstm_persist<<<NWG, 256, lds_bytes, stream>>>(Wp, Xb, bias, Hb, dw, db, out, bar);
}